// Round 3
// baseline (148.073 us; speedup 1.0000x reference)
//
#include <hip/hip_runtime.h>
#include <float.h>

// Problem constants (fixed by the reference): B=2, N=M=8192, G=256
#define B_ 2
#define N_ 8192
#define G_ 256
// CELL = abs(2*(-35)/256) = 70/256 = 0.2734375 exactly representable in fp32
constexpr float X_MIN_F = -35.0f;
constexpr float CELL_F  = 0.2734375f;

using u64 = unsigned long long;

// Workspace layout (bytes):
//   grid    i32[B*G*G]      [0, 524288)          packed (n<<1)|label, -1 invalid
//   accum   16B             [524288, 524304)     {float sum, int cnt, uint ticket}
//   px      u64[CC][B*N]    [524544, ...)        per-chunk packed (distbits<<32)|idx
//   py      f32[CC][B*N]    after px             per-chunk min dist (y-direction)
#define OFF_ACCUM 524288
#define OFF_PX    524544

// ---------------------------------------------------------------------------
// init: grid = -1 (0xFFFFFFFF), accum = 0. Partials need no init (fully
// written by nn_kernel). 32768 uint4 for grid + 1 for accum.
// ---------------------------------------------------------------------------
__global__ __launch_bounds__(256) void init_kernel(uint4* __restrict__ grid4,
                                                   uint4* __restrict__ accum4)
{
    int i = blockIdx.x * 256 + threadIdx.x;
    if (i < 32768) grid4[i] = make_uint4(~0u, ~0u, ~0u, ~0u);
    if (i == 32768) *accum4 = make_uint4(0u, 0u, 0u, 0u);
}

// ---------------------------------------------------------------------------
// 1-NN (L1), split-K over CC column chunks, NO atomics: each block writes its
// chunk-local best to px/py with plain coalesced stores.
//   blockIdx.z = dir*2 + b  (dir 0: p_i vs p_j, tracks argmin; dir 1: p_j vs
//   p_i, min-dist only — the reference discards that argmin).
//   4 rows/thread register tiling; columns staged in LDS (tight xyz pack,
//   read back as float4 -> ds_read_b128 same-address broadcast).
// ---------------------------------------------------------------------------
template<int CC>
__global__ __launch_bounds__(256) void nn_kernel(const float* __restrict__ p_i,
                                                 const float* __restrict__ p_j,
                                                 u64* __restrict__ px,
                                                 float* __restrict__ py)
{
    constexpr int COLS = N_ / CC;
    const int dir  = blockIdx.z >> 1;
    const int b    = blockIdx.z & 1;
    const int tid  = threadIdx.x;
    const int row0 = blockIdx.x * 1024 + tid * 4;
    const int c0   = blockIdx.y * COLS;

    const float* __restrict__ P = dir ? p_j : p_i;
    const float* __restrict__ Q = dir ? p_i : p_j;

    __shared__ __align__(16) float q[COLS * 3];
    for (int t = tid; t < COLS * 3 / 4; t += 256)
        ((float4*)q)[t] = ((const float4*)(Q + ((size_t)b * N_ + c0) * 3))[t];

    // 4 consecutive rows = 12 consecutive floats = 3 float4
    const float4* pp = (const float4*)(P + ((size_t)b * N_ + row0) * 3);
    float4 r0 = pp[0], r1 = pp[1], r2 = pp[2];
    float px_[4] = {r0.x, r0.w, r1.z, r2.y};
    float py_[4] = {r0.y, r1.x, r1.w, r2.z};
    float pz_[4] = {r0.z, r1.y, r2.x, r2.w};

    float best[4]; int bidx[4];
#pragma unroll
    for (int r = 0; r < 4; r++) { best[r] = FLT_MAX; bidx[r] = c0; }

    __syncthreads();

    if (dir == 0) {
        for (int j4 = 0; j4 < COLS; j4 += 4) {
            float4 a  = *(const float4*)&q[j4 * 3];
            float4 bb = *(const float4*)&q[j4 * 3 + 4];
            float4 cc = *(const float4*)&q[j4 * 3 + 8];
            float qx[4] = {a.x, a.w, bb.z, cc.y};
            float qy[4] = {a.y, bb.x, bb.w, cc.z};
            float qz[4] = {a.z, bb.y, cc.x, cc.w};
#pragma unroll
            for (int k = 0; k < 4; k++) {
                int jj = c0 + j4 + k;
#pragma unroll
                for (int r = 0; r < 4; r++) {
                    // bit-match reference: (|d0| + |d1|) + |d2|, left-assoc
                    float d = (fabsf(px_[r] - qx[k]) + fabsf(py_[r] - qy[k]))
                              + fabsf(pz_[r] - qz[k]);
                    bool lt = d < best[r];   // strict < -> first occurrence
                    best[r] = lt ? d : best[r];
                    bidx[r] = lt ? jj : bidx[r];
                }
            }
        }
        const size_t o = (size_t)blockIdx.y * (B_ * N_) + b * N_ + row0;
#pragma unroll
        for (int r = 0; r < 4; r++) {
            // non-negative fp32 bits order like unsigned; idx in low bits ->
            // u64 min over chunks keeps (min dist, then min idx) = first occ.
            px[o + r] = ((u64)__float_as_uint(best[r]) << 32) | (unsigned)bidx[r];
        }
    } else {
        for (int j4 = 0; j4 < COLS; j4 += 4) {
            float4 a  = *(const float4*)&q[j4 * 3];
            float4 bb = *(const float4*)&q[j4 * 3 + 4];
            float4 cc = *(const float4*)&q[j4 * 3 + 8];
            float qx[4] = {a.x, a.w, bb.z, cc.y};
            float qy[4] = {a.y, bb.x, bb.w, cc.z};
            float qz[4] = {a.z, bb.y, cc.x, cc.w};
#pragma unroll
            for (int k = 0; k < 4; k++) {
#pragma unroll
                for (int r = 0; r < 4; r++) {
                    float d = (fabsf(px_[r] - qx[k]) + fabsf(py_[r] - qy[k]))
                              + fabsf(pz_[r] - qz[k]);
                    best[r] = fminf(best[r], d);
                }
            }
        }
        const size_t o = (size_t)blockIdx.y * (B_ * N_) + b * N_ + row0;
#pragma unroll
        for (int r = 0; r < 4; r++) py[o + r] = best[r];
    }
}

// ---------------------------------------------------------------------------
// Fused cross-chunk reduce + per-point label + grid scatter.
// Last-write-wins in point order n == max n wins -> atomicMax on packed
// (n<<1 | label); grid initialized to -1 (invalid).
// ---------------------------------------------------------------------------
template<int CC>
__global__ __launch_bounds__(256) void reduce_scatter_kernel(
    const u64* __restrict__ px, const float* __restrict__ py,
    const float* __restrict__ flow, const int* __restrict__ nflow,
    const float* __restrict__ Pj, int* __restrict__ grid)
{
    int i = blockIdx.x * 256 + threadIdx.x;      // i in [0, B*N)
    int b = i >> 13;                             // N = 8192
    int n = i & (N_ - 1);

    u64 bx = px[i];
#pragma unroll 4
    for (int c = 1; c < CC; c++) {
        u64 v = px[(size_t)c * (B_ * N_) + i];
        bx = v < bx ? v : bx;
    }
    float by = py[i];
#pragma unroll 4
    for (int c = 1; c < CC; c++) by = fminf(by, py[(size_t)c * (B_ * N_) + i]);

    float dx = __uint_as_float((unsigned)(bx >> 32));
    float rigid = (dx + by) * 0.5f;

    bool dyn  = flow[i] > rigid;
    int label = dyn ? 1 : 0;
    int idx   = dyn ? nflow[i] : (int)(unsigned)(bx & 0xFFFFFFFFull);

    const float* qp = Pj + ((size_t)b * N_ + idx) * 3;
    float x = qp[0], y = qp[1];

    // bit-match reference: (p - shift) / CELL, IEEE fp32 divide, trunc cast
    int cx = (int)((x - X_MIN_F) / CELL_F);
    int cy = (int)((y - X_MIN_F) / CELL_F);

    atomicMax(&grid[(b << 16) + cx * G_ + cy], (n << 1) | label);
}

// ---------------------------------------------------------------------------
// Cross-entropy over valid grid cells + fused finalize: last block (ticket)
// reads the device-scope accumulators and writes the loss.
// ---------------------------------------------------------------------------
__global__ __launch_bounds__(256) void ce_kernel(const float* __restrict__ mos,
                                                 const int* __restrict__ grid,
                                                 float* __restrict__ accum,
                                                 float* __restrict__ out)
{
    int i = blockIdx.x * 256 + threadIdx.x;      // i in [0, B*G*G) = 131072
    float lsum = 0.0f;
    int   lcnt = 0;

    int packed = grid[i];
    if (packed >= 0) {
        int b    = i >> 16;                      // G*G = 65536
        int cell = i & 0xFFFF;
        float m0 = mos[((size_t)b * 2 + 0) * 65536 + cell];
        float m1 = mos[((size_t)b * 2 + 1) * 65536 + cell];
        float mx = fmaxf(m0, m1);
        float lse = logf(expf(m0 - mx) + expf(m1 - mx));
        float sh  = ((packed & 1) ? m1 : m0) - mx;   // stable log_softmax
        lsum = sh - lse;
        lcnt = 1;
    }

    // wave-64 shuffle reduction
#pragma unroll
    for (int o = 32; o > 0; o >>= 1) {
        lsum += __shfl_down(lsum, o);
        lcnt += __shfl_down(lcnt, o);
    }
    __shared__ float wsum[4];
    __shared__ int   wcnt[4];
    int wave = threadIdx.x >> 6;
    if ((threadIdx.x & 63) == 0) { wsum[wave] = lsum; wcnt[wave] = lcnt; }
    __syncthreads();
    if (threadIdx.x == 0) {
        float s = wsum[0] + wsum[1] + wsum[2] + wsum[3];
        int   c = wcnt[0] + wcnt[1] + wcnt[2] + wcnt[3];
        atomicAdd(&accum[0], s);
        atomicAdd((int*)&accum[1], c);
        __threadfence();
        unsigned t = atomicAdd((unsigned*)&accum[2], 1u);
        if (t == gridDim.x - 1) {
            float S = atomicAdd(&accum[0], 0.0f);
            int   C = atomicAdd((int*)&accum[1], 0);
            out[0] = -S / (float)(C > 0 ? C : 1);
        }
    }
}

// ---------------------------------------------------------------------------
template<int CC>
static void run(const float* p_i, const float* mos, const float* p_j,
                const float* flow, const int* nflow, float* out,
                char* ws, hipStream_t stream)
{
    int*   grid  = (int*)ws;
    float* accum = (float*)(ws + OFF_ACCUM);
    u64*   px    = (u64*)(ws + OFF_PX);
    float* py    = (float*)(ws + OFF_PX + (size_t)CC * B_ * N_ * 8);

    init_kernel<<<129, 256, 0, stream>>>((uint4*)grid, (uint4*)accum);

    dim3 g(N_ / 1024, CC, 4);                    // (8, CC, 4)
    nn_kernel<CC><<<g, 256, 0, stream>>>(p_i, p_j, px, py);

    reduce_scatter_kernel<CC><<<(B_ * N_) / 256, 256, 0, stream>>>(
        px, py, flow, nflow, p_j, grid);
    ce_kernel<<<(B_ * G_ * G_) / 256, 256, 0, stream>>>(mos, grid, accum, out);
}

extern "C" void kernel_launch(void* const* d_in, const int* in_sizes, int n_in,
                              void* d_out, int out_size, void* d_ws, size_t ws_size,
                              hipStream_t stream)
{
    const float* p_i   = (const float*)d_in[0];   // (B,N,3)
    const float* mos   = (const float*)d_in[1];   // (B,2,G,G)
    const float* p_j   = (const float*)d_in[2];   // (B,M,3)
    const float* flow  = (const float*)d_in[3];   // (B,N)
    const int*   nflow = (const int*)d_in[4];     // (B,N,1)
    float* out = (float*)d_out;
    char* ws = (char*)d_ws;

    // scratch: OFF_PX + CC*B*N*(8+4) bytes. CC=32 -> ~6.8 MB, CC=4 -> ~1.3 MB
    if (ws_size >= OFF_PX + (size_t)32 * B_ * N_ * 12)
        run<32>(p_i, mos, p_j, flow, nflow, out, ws, stream);
    else
        run<4>(p_i, mos, p_j, flow, nflow, out, ws, stream);
}